// Round 2
// baseline (166.535 us; speedup 1.0000x reference)
//
#include <hip/hip_runtime.h>

typedef __attribute__((ext_vector_type(4))) float  f32x4;
typedef __attribute__((ext_vector_type(8))) short  bf16x8;
typedef __attribute__((ext_vector_type(4))) int    i32x4;
typedef __attribute__((ext_vector_type(2))) unsigned short u16x2;
typedef __attribute__((ext_vector_type(4))) unsigned short u16x4;

#define NRES 256
#define DPAIR 128
#define NHEAD 4
#define CDIM 32
// ws layout (bytes)
#define ZN_OFF    0u            // 65536*128 bf16 = 16 MiB   (aliased as o_buf after GEMM)
#define QKG_OFF   16777216u     // 65536*384 bf16 = 48 MiB   (cols: q 0-127, k 128-255, g 256-383)
#define VT_OFF    67108864u     // [256 i][4 h][32 c][256 j] bf16 = 16 MiB
#define BIAS_OFF  83886080u     // [4][256][256] f32 = 1 MiB
#define WCAT_OFF  84934656u     // [512][128] bf16 (q-scaled, k, v, g weights)
#define WO_OFF    85065728u     // [128][128] bf16

__device__ __forceinline__ unsigned short f2bf(float x){
  unsigned int u = __builtin_bit_cast(unsigned int, x);
  unsigned int r = (u + 0x7FFFu + ((u>>16)&1u)) >> 16;
  return (unsigned short)r;
}
__device__ __forceinline__ float bf2f(unsigned short b){
  unsigned int u = ((unsigned int)b) << 16;
  return __builtin_bit_cast(float, u);
}

// ---------------- kernel 1: weight prep (fp32 -> bf16, fold q scale) ----------------
__global__ __launch_bounds__(256) void prep_kernel(
    const float* __restrict__ w_qkv, const float* __restrict__ w_g,
    const float* __restrict__ w_o,
    unsigned short* __restrict__ Wcat, unsigned short* __restrict__ Wo_bf)
{
  int idx = blockIdx.x*256 + threadIdx.x;
  if (idx < 512*128){
    int r = idx >> 7, d = idx & 127;
    float v = (r < 384) ? w_qkv[idx] : w_g[(r-384)*128 + d];
    if (r < 128) v *= 0.17677669529663689f;   // C^-0.5 folded into q rows
    Wcat[idx] = f2bf(v);
  } else if (idx < 512*128 + 128*128){
    int k = idx - 65536;
    Wo_bf[k] = f2bf(w_o[k]);
  }
}

// ---------------- kernel 2: LayerNorm (of transposed Z_raw) + pair-bias GEMV --------
// one wave per output row m = i*256+j ; Zn[m][d] = LN(Z_raw[j][i][:])[d]
__global__ __launch_bounds__(256) void ln_bias_kernel(
    const float* __restrict__ Z_raw, const float* __restrict__ ln_gamma,
    const float* __restrict__ ln_beta, const float* __restrict__ w_b,
    unsigned short* __restrict__ Zn, float* __restrict__ bias_buf)
{
  int wid = threadIdx.x >> 6, lane = threadIdx.x & 63;
  int m = blockIdx.x*4 + wid;
  int i = m >> 8, j = m & 255;
  float2 z2 = *reinterpret_cast<const float2*>(&Z_raw[((size_t)(j*256 + i))*128 + lane*2]);
  float s  = z2.x + z2.y;
  float sq = z2.x*z2.x + z2.y*z2.y;
  #pragma unroll
  for (int mk=1; mk<64; mk<<=1){ s += __shfl_xor(s, mk, 64); sq += __shfl_xor(sq, mk, 64); }
  float mu   = s * (1.0f/128.0f);
  float var  = sq*(1.0f/128.0f) - mu*mu;
  float rstd = rsqrtf(var + 1e-5f);
  float zn0 = (z2.x - mu)*rstd*ln_gamma[lane*2]   + ln_beta[lane*2];
  float zn1 = (z2.y - mu)*rstd*ln_gamma[lane*2+1] + ln_beta[lane*2+1];
  u16x2 o; o.x = f2bf(zn0); o.y = f2bf(zn1);
  *reinterpret_cast<u16x2*>(&Zn[(size_t)m*128 + lane*2]) = o;
  // pair bias: bias[h][i][j] = Zn(i,j,:) . w_b[h,:]
  #pragma unroll
  for (int h=0; h<4; ++h){
    float d = zn0*w_b[h*128 + lane*2] + zn1*w_b[h*128 + lane*2 + 1];
    #pragma unroll
    for (int mk=1; mk<64; mk<<=1) d += __shfl_xor(d, mk, 64);
    if (lane == 0) bias_buf[((size_t)h*256 + i)*256 + j] = d;
  }
}

// ---------------- kernel 3: fused qkv+g GEMM [65536x128] x [128x512] ---------------
// cb 0: q -> QKG cols 0-127 ; cb 1: k -> cols 128-255 ; cb 2: v -> Vt transposed ;
// cb 3: g -> QKG cols 256-383
__global__ __launch_bounds__(256) void gemm_qkvg_kernel(
    const unsigned short* __restrict__ Zn, const unsigned short* __restrict__ Wcat,
    unsigned short* __restrict__ QKG, unsigned short* __restrict__ Vt)
{
  __shared__ __align__(16) char sA[32768];   // [128 rows][256 B] swizzled
  __shared__ __align__(16) char sB[32768];
  int rb = blockIdx.x, cb = blockIdx.y;
  int t = threadIdx.x;
  const char* gA = (const char*)Zn   + (size_t)rb*32768;
  const char* gB = (const char*)Wcat + (size_t)cb*32768;
  #pragma unroll
  for (int it=0; it<8; ++it){
    int off = it*4096 + t*16;
    int row = off >> 8;
    int swz = off ^ ((row&7)<<4);
    *reinterpret_cast<i32x4*>(sA + swz) = *reinterpret_cast<const i32x4*>(gA + off);
    *reinterpret_cast<i32x4*>(sB + swz) = *reinterpret_cast<const i32x4*>(gB + off);
  }
  __syncthreads();
  int wid = t>>6, lane = t&63;
  int wr = wid>>1, wc = wid&1;
  int lcol = lane & 15, lk16 = (lane>>4)*16;
  f32x4 acc[4][4] = {};
  #pragma unroll
  for (int ks=0; ks<4; ++ks){
    bf16x8 a[4], b[4];
    #pragma unroll
    for (int mi=0; mi<4; ++mi){
      int row = wr*64 + mi*16 + lcol;
      int off = row*256 + ks*64 + lk16;
      a[mi] = *reinterpret_cast<const bf16x8*>(sA + (off ^ ((row&7)<<4)));
    }
    #pragma unroll
    for (int ni=0; ni<4; ++ni){
      int row = wc*64 + ni*16 + lcol;
      int off = row*256 + ks*64 + lk16;
      b[ni] = *reinterpret_cast<const bf16x8*>(sB + (off ^ ((row&7)<<4)));
    }
    #pragma unroll
    for (int mi=0; mi<4; ++mi)
      #pragma unroll
      for (int ni=0; ni<4; ++ni)
        acc[mi][ni] = __builtin_amdgcn_mfma_f32_16x16x32_bf16(a[mi], b[ni], acc[mi][ni], 0,0,0);
  }
  int r0 = (lane>>4)*4;
  if (cb != 2){
    int colbase = (cb < 2 ? cb*128 : 256) + wc*64;
    #pragma unroll
    for (int mi=0; mi<4; ++mi)
      #pragma unroll
      for (int ni=0; ni<4; ++ni){
        int col  = colbase + ni*16 + lcol;
        int mrow = rb*128 + wr*64 + mi*16 + r0;
        #pragma unroll
        for (int r=0; r<4; ++r)
          QKG[(size_t)(mrow+r)*384 + col] = f2bf(acc[mi][ni][r]);
      }
  } else {
    #pragma unroll
    for (int mi=0; mi<4; ++mi)
      #pragma unroll
      for (int ni=0; ni<4; ++ni){
        int e = wc*64 + ni*16 + lcol;      // v channel: h = e>>5, c = e&31
        int h = e>>5, c = e&31;
        int mrow = rb*128 + wr*64 + mi*16 + r0;
        int i = mrow >> 8, j = mrow & 255;
        u16x4 pk;
        #pragma unroll
        for (int r=0; r<4; ++r) pk[r] = f2bf(acc[mi][ni][r]);
        *reinterpret_cast<u16x4*>(&Vt[(size_t)((i*4 + h)*32 + c)*256 + j]) = pk;
      }
  }
}

// ---------------- kernel 4: attention, one block per (i, h) ------------------------
__global__ __launch_bounds__(256) void attn_kernel(
    const unsigned short* __restrict__ QKG, const unsigned short* __restrict__ Vt,
    const float* __restrict__ bias_buf, const float* __restrict__ Z_mask,
    unsigned short* __restrict__ o_buf)
{
  __shared__ __align__(16) char sK[16384];   // [256 k-rows][64 B] swizzled
  __shared__ __align__(16) char sV[16384];   // [32 c-rows][512 B] swizzled
  __shared__ __align__(16) char sP[32768];   // per-wave [16 rows][512 B] swizzled
  __shared__ float smask[256];
  int ia = blockIdx.x >> 2, h = blockIdx.x & 3;
  int t = threadIdx.x;
  { // stage K rows (k-projection cols 128..159+h*32)
    const unsigned short* src = &QKG[(size_t)(ia*256 + t)*384 + 128 + h*32];
    #pragma unroll
    for (int c16=0; c16<4; ++c16){
      int off = t*64 + c16*16;
      *reinterpret_cast<i32x4*>(sK + (off ^ ((t&7)<<4))) =
        *reinterpret_cast<const i32x4*>(src + c16*8);
    }
  }
  { // stage V^T (contiguous 16 KiB slab)
    const char* src = (const char*)&Vt[(size_t)(ia*4 + h)*32*256];
    #pragma unroll
    for (int it=0; it<4; ++it){
      int off = (it*256 + t)*16;
      int row = off >> 9;
      *reinterpret_cast<i32x4*>(sV + (off ^ ((row&7)<<4))) =
        *reinterpret_cast<const i32x4*>(src + off);
    }
  }
  smask[t] = 1e9f * (Z_mask[(size_t)t*256 + ia] - 1.0f);
  __syncthreads();

  int wid = t>>6, lane = t&63;
  int lcol = lane & 15, lk16 = (lane>>4)*16;
  char* sPw = sP + wid*8192;
  int r0 = (lane>>4)*4;

  for (int mi=0; mi<4; ++mi){
    int q0 = wid*64 + mi*16;
    bf16x8 aq = *reinterpret_cast<const bf16x8*>(
        &QKG[(size_t)(ia*256 + q0 + lcol)*384 + h*32 + (lane>>4)*8]);
    f32x4 s[16];
    #pragma unroll
    for (int ni=0; ni<16; ++ni){
      int krow = ni*16 + lcol;
      int off  = krow*64 + lk16;
      bf16x8 bk = *reinterpret_cast<const bf16x8*>(sK + (off ^ ((krow&7)<<4)));
      f32x4 z = {0.f,0.f,0.f,0.f};
      s[ni] = __builtin_amdgcn_mfma_f32_16x16x32_bf16(aq, bk, z, 0,0,0);
    }
    float rsum[4];
    #pragma unroll
    for (int r=0; r<4; ++r){
      int q = q0 + r0 + r;
      float mx = -3.0e38f;
      #pragma unroll
      for (int ni=0; ni<16; ++ni){
        int kk = ni*16 + lcol;
        float v = s[ni][r] + bias_buf[((size_t)h*256 + q)*256 + kk] + smask[kk];
        s[ni][r] = v;
        mx = fmaxf(mx, v);
      }
      #pragma unroll
      for (int mk=1; mk<16; mk<<=1) mx = fmaxf(mx, __shfl_xor(mx, mk, 64));
      float sum = 0.f;
      #pragma unroll
      for (int ni=0; ni<16; ++ni){
        float p = __expf(s[ni][r] - mx);
        s[ni][r] = p;
        sum += p;
      }
      #pragma unroll
      for (int mk=1; mk<16; mk<<=1) sum += __shfl_xor(sum, mk, 64);
      rsum[r] = sum;
    }
    // P -> LDS (bf16, swizzled), then PV
    #pragma unroll
    for (int ni=0; ni<16; ++ni){
      int kk = ni*16 + lcol;
      #pragma unroll
      for (int r=0; r<4; ++r){
        int rp = r0 + r;
        int off = rp*512 + kk*2;
        *reinterpret_cast<unsigned short*>(sPw + (off ^ ((rp&7)<<4))) = f2bf(s[ni][r]);
      }
    }
    __syncthreads();
    f32x4 oacc[2] = {};
    #pragma unroll
    for (int ks=0; ks<8; ++ks){
      int poff = lcol*512 + ks*64 + lk16;
      bf16x8 ap = *reinterpret_cast<const bf16x8*>(sPw + (poff ^ ((lcol&7)<<4)));
      #pragma unroll
      for (int nc=0; nc<2; ++nc){
        int vrow = nc*16 + lcol;
        int voff = vrow*512 + ks*64 + lk16;
        bf16x8 bv = *reinterpret_cast<const bf16x8*>(sV + (voff ^ ((vrow&7)<<4)));
        oacc[nc] = __builtin_amdgcn_mfma_f32_16x16x32_bf16(ap, bv, oacc[nc], 0,0,0);
      }
    }
    #pragma unroll
    for (int nc=0; nc<2; ++nc)
      #pragma unroll
      for (int r=0; r<4; ++r){
        int q = q0 + r0 + r;
        float val = oacc[nc][r] / rsum[r];
        o_buf[(size_t)(ia*256 + q)*128 + h*32 + nc*16 + lcol] = f2bf(val);
      }
    __syncthreads();
  }
}

// ---------------- kernel 5: gate * o @ w_o^T + out_bias + Z_raw (transposed out) ----
__global__ __launch_bounds__(256) void final_kernel(
    const unsigned short* __restrict__ QKG, const unsigned short* __restrict__ o_buf,
    const unsigned short* __restrict__ Wo_bf, const float* __restrict__ b_g,
    const float* __restrict__ out_bias, const float* __restrict__ Z_raw,
    float* __restrict__ out)
{
  __shared__ __align__(16) char sA[32768];
  __shared__ __align__(16) char sB[32768];
  int rb = blockIdx.x, t = threadIdx.x;
  #pragma unroll
  for (int it=0; it<8; ++it){
    int idx = (it*256 + t)*8;
    int row = idx >> 7, e0 = idx & 127;
    size_t m = (size_t)rb*128 + row;
    bf16x8 gv = *reinterpret_cast<const bf16x8*>(&QKG[m*384 + 256 + e0]);
    bf16x8 ov = *reinterpret_cast<const bf16x8*>(&o_buf[m*128 + e0]);
    bf16x8 av;
    #pragma unroll
    for (int jj=0; jj<8; ++jj){
      float g  = bf2f((unsigned short)gv[jj]) + b_g[e0+jj];
      float sg = 1.0f/(1.0f + __expf(-g));
      av[jj] = (short)f2bf(sg * bf2f((unsigned short)ov[jj]));
    }
    int off = idx*2;
    *reinterpret_cast<bf16x8*>(sA + (off ^ ((row&7)<<4))) = av;
    *reinterpret_cast<i32x4*>(sB + (off ^ ((row&7)<<4))) =
      *reinterpret_cast<const i32x4*>(&Wo_bf[idx]);
  }
  __syncthreads();
  int wid = t>>6, lane = t&63;
  int wr = wid>>1, wc = wid&1;
  int lcol = lane & 15, lk16 = (lane>>4)*16;
  f32x4 acc[4][4] = {};
  #pragma unroll
  for (int ks=0; ks<4; ++ks){
    bf16x8 a[4], b[4];
    #pragma unroll
    for (int mi=0; mi<4; ++mi){
      int row = wr*64 + mi*16 + lcol;
      int off = row*256 + ks*64 + lk16;
      a[mi] = *reinterpret_cast<const bf16x8*>(sA + (off ^ ((row&7)<<4)));
    }
    #pragma unroll
    for (int ni=0; ni<4; ++ni){
      int row = wc*64 + ni*16 + lcol;
      int off = row*256 + ks*64 + lk16;
      b[ni] = *reinterpret_cast<const bf16x8*>(sB + (off ^ ((row&7)<<4)));
    }
    #pragma unroll
    for (int mi=0; mi<4; ++mi)
      #pragma unroll
      for (int ni=0; ni<4; ++ni)
        acc[mi][ni] = __builtin_amdgcn_mfma_f32_16x16x32_bf16(a[mi], b[ni], acc[mi][ni], 0,0,0);
  }
  int r0 = (lane>>4)*4;
  #pragma unroll
  for (int mi=0; mi<4; ++mi)
    #pragma unroll
    for (int ni=0; ni<4; ++ni){
      int col = wc*64 + ni*16 + lcol;
      #pragma unroll
      for (int r=0; r<4; ++r){
        int mrow = rb*128 + wr*64 + mi*16 + r0 + r;
        int i = mrow >> 8, j = mrow & 255;
        size_t oidx = ((size_t)(j*256 + i))*128 + col;
        out[oidx] = acc[mi][ni][r] + out_bias[col] + Z_raw[oidx];
      }
    }
}

extern "C" void kernel_launch(void* const* d_in, const int* in_sizes, int n_in,
                              void* d_out, int out_size, void* d_ws, size_t ws_size,
                              hipStream_t stream)
{
  (void)in_sizes; (void)n_in; (void)out_size; (void)ws_size;
  const float* Z_raw    = (const float*)d_in[0];
  const float* Z_mask   = (const float*)d_in[1];
  const float* ln_gamma = (const float*)d_in[2];
  const float* ln_beta  = (const float*)d_in[3];
  const float* w_b      = (const float*)d_in[4];
  const float* w_qkv    = (const float*)d_in[5];
  const float* w_g      = (const float*)d_in[6];
  const float* b_g      = (const float*)d_in[7];
  const float* w_o      = (const float*)d_in[8];
  const float* out_bias = (const float*)d_in[9];
  float* out = (float*)d_out;

  char* ws = (char*)d_ws;
  unsigned short* Zn    = (unsigned short*)(ws + ZN_OFF);
  unsigned short* QKG   = (unsigned short*)(ws + QKG_OFF);
  unsigned short* Vt    = (unsigned short*)(ws + VT_OFF);
  float*          biasb = (float*)(ws + BIAS_OFF);
  unsigned short* Wcat  = (unsigned short*)(ws + WCAT_OFF);
  unsigned short* Wo_bf = (unsigned short*)(ws + WO_OFF);
  unsigned short* o_buf = Zn;   // alias: Zn dead after GEMM

  prep_kernel<<<dim3(320), dim3(256), 0, stream>>>(w_qkv, w_g, w_o, Wcat, Wo_bf);
  ln_bias_kernel<<<dim3(16384), dim3(256), 0, stream>>>(Z_raw, ln_gamma, ln_beta, w_b, Zn, biasb);
  gemm_qkvg_kernel<<<dim3(512, 4), dim3(256), 0, stream>>>(Zn, Wcat, QKG, Vt);
  attn_kernel<<<dim3(1024), dim3(256), 0, stream>>>(QKG, Vt, biasb, Z_mask, o_buf);
  final_kernel<<<dim3(512), dim3(256), 0, stream>>>(QKG, o_buf, Wo_bf, b_g, out_bias, Z_raw, out);
}